// Round 11
// baseline (333.728 us; speedup 1.0000x reference)
//
#include <hip/hip_runtime.h>
#include <hip/hip_bf16.h>

#define S_LEN 2048
#define DH    64
#define NBH   32          // B*H
#define KVT   32          // keys per tile
#define NT    64          // tiles per bh (S/KVT)

typedef __attribute__((ext_vector_type(8)))  short short8;
typedef __attribute__((ext_vector_type(4)))  float f32x4;
typedef __attribute__((ext_vector_type(16))) float f32x16;

static __device__ __forceinline__ unsigned cvtpk_bf16(float a, float b) {
    unsigned r;
    asm("v_cvt_pk_bf16_f32 %0, %1, %2" : "=v"(r) : "v"(a), "v"(b));
    return r;
}
// cross-half (lane ^ 32) reductions — __shfl_xor is proven on this target.
// (permlane32_swap with two identical "+v" operands gets register-coalesced
//  into a self-swap, dropping each lane's own half. Do not reintroduce.)
static __device__ __forceinline__ float xor32_max(float x) {
    return fmaxf(x, __shfl_xor(x, 32));
}
static __device__ __forceinline__ float xor32_add(float x) {
    return x + __shfl_xor(x, 32);
}

// ---------------------------------------------------------------------------
// prep: K,V fp32 -> bf16 fragment images (4 KB per 32-key tile).
// Kimg tile: [key 0..31][128B = 64 d bf16]   (MFMA A-operand rows)
// Vimg tile: [d 0..63][64B = 32 keys bf16]   (V^T, PV A-operand rows)
// ---------------------------------------------------------------------------
__global__ __launch_bounds__(256)
void prep_kernel(const float* __restrict__ K, const float* __restrict__ V,
                 char* __restrict__ Kimg, char* __restrict__ Vimg)
{
    const int t = blockIdx.x, bh = blockIdx.y, tid = threadIdx.x;
    const long tileOff = ((long)bh * NT + t) * 4096;
    const float* kp = K + (long)bh * S_LEN * DH + t * KVT * DH;
    const float* vp = V + (long)bh * S_LEN * DH + t * KVT * DH;

    {   // K rows
        int key = tid >> 3, dc = tid & 7;
        f32x4 x = *(const f32x4*)(kp + key * 64 + dc * 8);
        f32x4 y = *(const f32x4*)(kp + key * 64 + dc * 8 + 4);
        uint4 w;
        w.x = cvtpk_bf16(x[0], x[1]);
        w.y = cvtpk_bf16(x[2], x[3]);
        w.z = cvtpk_bf16(y[0], y[1]);
        w.w = cvtpk_bf16(y[2], y[3]);
        *(uint4*)(Kimg + tileOff + key * 128 + dc * 16) = w;
    }
    {   // V^T rows (4x2 micro-transpose per thread)
        int vdg = tid & 15, vkq = tid >> 4;
        int d0 = vdg * 4, k0 = vkq * 2;
        f32x4 x0 = *(const f32x4*)(vp + k0 * 64 + d0);
        f32x4 x1 = *(const f32x4*)(vp + (k0 + 1) * 64 + d0);
        #pragma unroll
        for (int i = 0; i < 4; ++i)
            *(unsigned*)(Vimg + tileOff + (d0 + i) * 64 + k0 * 2) = cvtpk_bf16(x0[i], x1[i]);
    }
}

__global__ void fz_kernel(const int* __restrict__ pad, int* __restrict__ fz)
{
    int b = blockIdx.x;
    __shared__ int red[256];
    int local = S_LEN;
    for (int k = threadIdx.x; k < S_LEN; k += 256)
        if (pad[b * S_LEN + k] == 0 && k < local) local = k;
    red[threadIdx.x] = local;
    __syncthreads();
    for (int s = 128; s > 0; s >>= 1) {
        if (threadIdx.x < s) red[threadIdx.x] = min(red[threadIdx.x], red[threadIdx.x + s]);
        __syncthreads();
    }
    if (threadIdx.x == 0) fz[b] = red[0];
}

__global__ __launch_bounds__(1024)
void bias_kernel(const int* __restrict__ pad, float* __restrict__ bias)
{
    int b = blockIdx.x;
    #pragma unroll
    for (int i = 0; i < 2; ++i) {
        int k = threadIdx.x + i * 1024;
        bias[b * S_LEN + k] = pad[b * S_LEN + k] ? -1e30f : 0.f;
    }
}

__global__ __launch_bounds__(1024)
void meanv_kernel(const float* __restrict__ V, const int* __restrict__ fz,
                  float* __restrict__ meanv)
{
    const int bh = blockIdx.x;
    const int b  = bh >> 4;
    if (fz[b] <= 0) return;
    const int d4 = threadIdx.x & 15;
    const int kp = threadIdx.x >> 4;
    const float* vp = V + (long)bh * S_LEN * DH;
    f32x4 acc = (f32x4){0.f, 0.f, 0.f, 0.f};
    #pragma unroll 4
    for (int k = kp; k < S_LEN; k += 64)
        acc += *(const f32x4*)(vp + (long)k * DH + d4 * 4);
    __shared__ f32x4 red[64][16];
    red[kp][d4] = acc;
    __syncthreads();
    #pragma unroll
    for (int s = 32; s >= 1; s >>= 1) {
        if (kp < s) red[kp][d4] += red[kp + s][d4];
        __syncthreads();
    }
    if (kp == 0)
        *(f32x4*)(meanv + bh * DH + d4 * 4) = red[0][d4] * (1.0f / 2048.0f);
}

// ---------------------------------------------------------------------------
// attn v8: split-KV. One block (4 waves) per (bh,bx) item; wave w owns tiles
// {w, w+4, ...} (longest wave 64 -> 16 tiles), then LDS merge with weights
// exp2(m_w - m*). Empty / all-masked waves contribute weight exactly 0 in
// fp32, so their junk is wiped (same algebra as the in-loop prefix wipe).
// Mapping r10-verbatim: XCD locality (FETCH 70->16.5 MB proven) + balance.
// ---------------------------------------------------------------------------
#define LOADK(dst, tt) do { const char* _p = KB + (long)(tt) * 4096 + lq * 128 + hi * 16; \
    dst[0] = *(const short8*)(_p);       dst[1] = *(const short8*)(_p + 32);  \
    dst[2] = *(const short8*)(_p + 64);  dst[3] = *(const short8*)(_p + 96); } while (0)
#define LOADV(dst, tt) do { const char* _p = VB + (long)(tt) * 4096 + lq * 64 + hi * 16; \
    dst[0] = *(const short8*)(_p);        dst[1] = *(const short8*)(_p + 32); \
    dst[2] = *(const short8*)(_p + 2048); dst[3] = *(const short8*)(_p + 2048 + 32); } while (0)
#define LOADB(dst, tt) do { const float* _p = biasB + (tt) * 32 + hi * 4; \
    dst[0] = *(const f32x4*)(_p);      dst[1] = *(const f32x4*)(_p + 8); \
    dst[2] = *(const f32x4*)(_p + 16); dst[3] = *(const f32x4*)(_p + 24); } while (0)

#define COMPUTE(TT, K_, V_, B_) do {                                          \
    f32x16 s0;                                                                \
    _Pragma("unroll")                                                         \
    for (int g = 0; g < 4; ++g) {                                             \
        f32x4 pb4 = B_[g];                                                    \
        _Pragma("unroll")                                                     \
        for (int i = 0; i < 4; ++i) s0[g * 4 + i] = pb4[i];                   \
    }                                                                         \
    __builtin_amdgcn_s_setprio(1);                                            \
    s0 = __builtin_amdgcn_mfma_f32_32x32x16_bf16(K_[0], bq[0], s0, 0, 0, 0);  \
    s0 = __builtin_amdgcn_mfma_f32_32x32x16_bf16(K_[1], bq[1], s0, 0, 0, 0);  \
    s0 = __builtin_amdgcn_mfma_f32_32x32x16_bf16(K_[2], bq[2], s0, 0, 0, 0);  \
    s0 = __builtin_amdgcn_mfma_f32_32x32x16_bf16(K_[3], bq[3], s0, 0, 0, 0);  \
    __builtin_amdgcn_s_setprio(0);                                            \
    if ((TT) == nkv - 1) {                                                    \
        _Pragma("unroll")                                                     \
        for (int rr = 0; rr < 16; ++rr) {                                     \
            int key_r = (rr & 3) + 8 * (rr >> 2) + 4 * hi;                    \
            if (key_r > lq) s0[rr] = -1e30f;                                  \
        }                                                                     \
    }                                                                         \
    float bmg[4];                                                             \
    _Pragma("unroll")                                                         \
    for (int g = 0; g < 4; ++g)                                               \
        bmg[g] = fmaxf(fmaxf(s0[g*4], s0[g*4+1]), fmaxf(s0[g*4+2], s0[g*4+3])); \
    float bm = fmaxf(fmaxf(bmg[0], bmg[1]), fmaxf(bmg[2], bmg[3]));           \
    bm = xor32_max(bm);                                                       \
    if (__any(bm > m_run + 8.0f)) {                                           \
        float mnew = fmaxf(m_run, bm);                                        \
        float c = exp2f(m_run - mnew);                                        \
        m_run = mnew; l_run *= c;                                             \
        _Pragma("unroll")                                                     \
        for (int rr = 0; rr < 16; ++rr) { o0[rr] *= c; o1[rr] *= c; }         \
    }                                                                         \
    _Pragma("unroll")                                                         \
    for (int rr = 0; rr < 16; ++rr) s0[rr] = exp2f(s0[rr] - m_run);           \
    float rsg[4];                                                             \
    _Pragma("unroll")                                                         \
    for (int g = 0; g < 4; ++g)                                               \
        rsg[g] = (s0[g*4] + s0[g*4+1]) + (s0[g*4+2] + s0[g*4+3]);             \
    float rs = (rsg[0] + rsg[1]) + (rsg[2] + rsg[3]);                         \
    l_run += xor32_add(rs);                                                   \
    short8 pfr0, pfr1;                                                        \
    {                                                                         \
        unsigned a0 = cvtpk_bf16(s0[0], s0[1]), b0 = cvtpk_bf16(s0[4], s0[5]);\
        asm("v_permlane32_swap_b32 %0, %1" : "+v"(a0), "+v"(b0));             \
        unsigned a1 = cvtpk_bf16(s0[2], s0[3]), b1 = cvtpk_bf16(s0[6], s0[7]);\
        asm("v_permlane32_swap_b32 %0, %1" : "+v"(a1), "+v"(b1));             \
        union { short8 s8; unsigned u[4]; } u;                                \
        u.u[0] = a0; u.u[1] = a1; u.u[2] = b0; u.u[3] = b1;                   \
        pfr0 = u.s8;                                                          \
    }                                                                         \
    {                                                                         \
        unsigned a0 = cvtpk_bf16(s0[8], s0[9]),  b0 = cvtpk_bf16(s0[12], s0[13]); \
        asm("v_permlane32_swap_b32 %0, %1" : "+v"(a0), "+v"(b0));             \
        unsigned a1 = cvtpk_bf16(s0[10], s0[11]), b1 = cvtpk_bf16(s0[14], s0[15]); \
        asm("v_permlane32_swap_b32 %0, %1" : "+v"(a1), "+v"(b1));             \
        union { short8 s8; unsigned u[4]; } u;                                \
        u.u[0] = a0; u.u[1] = a1; u.u[2] = b0; u.u[3] = b1;                   \
        pfr1 = u.s8;                                                          \
    }                                                                         \
    __builtin_amdgcn_s_setprio(1);                                            \
    o0 = __builtin_amdgcn_mfma_f32_32x32x16_bf16(V_[0], pfr0, o0, 0, 0, 0);   \
    o0 = __builtin_amdgcn_mfma_f32_32x32x16_bf16(V_[1], pfr1, o0, 0, 0, 0);   \
    o1 = __builtin_amdgcn_mfma_f32_32x32x16_bf16(V_[2], pfr0, o1, 0, 0, 0);   \
    o1 = __builtin_amdgcn_mfma_f32_32x32x16_bf16(V_[3], pfr1, o1, 0, 0, 0);   \
    __builtin_amdgcn_s_setprio(0);                                            \
} while (0)

__global__ __launch_bounds__(256, 3)
void attn_fwd8(const float* __restrict__ Q, const char* __restrict__ Kimg,
               const char* __restrict__ Vimg, const float* __restrict__ bias,
               float* __restrict__ out)
{
    __shared__ float mW[4][32];
    __shared__ float lW[4][32];
    __shared__ __align__(16) char ldsO[3][8192];   // waves 1..3: O (8KB each)

    const int tid  = threadIdx.x;
    const int lane = tid & 63;
    const int w    = tid >> 6;
    const int lq   = lane & 31, hi = lane >> 5;

    // r10 mapping (verbatim): XCD locality + balance, bijection over 2048
    const int gid = blockIdx.x;
    const int x   = gid & 7;
    const int c   = (gid >> 3) & 31;
    const int m   = (gid >> 8) & 3;
    const int s   = gid >> 10;
    const int bh  = x + 8 * (c & 3);
    const int e   = ((c >> 2) << 2) | m;     // 0..31
    const int bx  = s ? 63 - e : e;
    const int q0  = bx * 32;
    const int nkv = bx + 1;
    const long base = (long)bh * S_LEN * DH;

    const char*  KB    = Kimg + (long)bh * NT * 4096;
    const char*  VB    = Vimg + (long)bh * NT * 4096;
    const float* biasB = bias + (bh >> 4) * S_LEN;

    // Q fragments (B operand), scale = (1/8)*log2(e) folded
    const float QS = 0.18033688011112042f;
    short8 bq[4];
    {
        const float* qp = Q + base + (long)(q0 + lq) * DH;
        #pragma unroll
        for (int ss = 0; ss < 4; ++ss) {
            int d0 = ss * 16 + hi * 8;
            f32x4 xx = *(const f32x4*)(qp + d0);
            f32x4 yy = *(const f32x4*)(qp + d0 + 4);
            union { short8 s8; unsigned u4[4]; } uu;
            uu.u4[0] = cvtpk_bf16(xx[0] * QS, xx[1] * QS);
            uu.u4[1] = cvtpk_bf16(xx[2] * QS, xx[3] * QS);
            uu.u4[2] = cvtpk_bf16(yy[0] * QS, yy[1] * QS);
            uu.u4[3] = cvtpk_bf16(yy[2] * QS, yy[3] * QS);
            bq[ss] = uu.s8;
        }
    }

    f32x16 o0, o1;
    #pragma unroll
    for (int rr = 0; rr < 16; ++rr) { o0[rr] = 0.f; o1[rr] = 0.f; }
    float m_run = -1e30f, l_run = 0.f;

    // this wave's tiles: w, w+4, w+8, ...
    const int nw = (w < nkv) ? ((nkv - w + 3) >> 2) : 0;
#define TIDX(i) (w + 4 * (i))

    if (nw > 0) {
        short8 kA[4], kB_[4], kC[4], vA[4], vB_[4], vC[4];
        f32x4  bA[4], bB_[4], bC[4];

        LOADB(bA, TIDX(0));  LOADK(kA, TIDX(0));  LOADV(vA, TIDX(0));
        if (nw > 1) { LOADB(bB_, TIDX(1)); LOADK(kB_, TIDX(1)); LOADV(vB_, TIDX(1)); }

        int i = 0;
        for (;;) {
            if (i + 2 < nw) { LOADB(bC, TIDX(i+2));  LOADK(kC, TIDX(i+2));  LOADV(vC, TIDX(i+2)); }
            COMPUTE(TIDX(i), kA, vA, bA);
            ++i; if (i >= nw) break;
            if (i + 2 < nw) { LOADB(bA, TIDX(i+2));  LOADK(kA, TIDX(i+2));  LOADV(vA, TIDX(i+2)); }
            COMPUTE(TIDX(i), kB_, vB_, bB_);
            ++i; if (i >= nw) break;
            if (i + 2 < nw) { LOADB(bB_, TIDX(i+2)); LOADK(kB_, TIDX(i+2)); LOADV(vB_, TIDX(i+2)); }
            COMPUTE(TIDX(i), kC, vC, bC);
            ++i; if (i >= nw) break;
        }
    }

    // ---- merge ----
    mW[w][lq] = m_run;
    lW[w][lq] = l_run;
    if (w > 0) {
        char* dst = ldsO[w - 1] + lane * 128;
        #pragma unroll
        for (int g = 0; g < 4; ++g) {
            f32x4 a0, a1;
            #pragma unroll
            for (int i = 0; i < 4; ++i) { a0[i] = o0[g * 4 + i]; a1[i] = o1[g * 4 + i]; }
            *(f32x4*)(dst + ((g       ^ (lane & 7)) * 16)) = a0;
            *(f32x4*)(dst + (((4 + g) ^ (lane & 7)) * 16)) = a1;
        }
    }
    __syncthreads();
    if (w == 0) {
        float m0 = mW[0][lq], m1 = mW[1][lq], m2 = mW[2][lq], m3 = mW[3][lq];
        float ms = fmaxf(fmaxf(m0, m1), fmaxf(m2, m3));
        float w0 = exp2f(m0 - ms), w1 = exp2f(m1 - ms);
        float w2 = exp2f(m2 - ms), w3 = exp2f(m3 - ms);
        float ls = ((w0 * lW[0][lq] + w1 * lW[1][lq]) + (w2 * lW[2][lq] + w3 * lW[3][lq]));
        float invl = 1.0f / ls;

        const char* s1p = ldsO[0] + lane * 128;
        const char* s2p = ldsO[1] + lane * 128;
        const char* s3p = ldsO[2] + lane * 128;
        float* op = out + base + (long)(q0 + lq) * DH;
        #pragma unroll
        for (int g = 0; g < 4; ++g) {
            int c0 = (g       ^ (lane & 7)) * 16;
            int c1 = ((4 + g) ^ (lane & 7)) * 16;
            f32x4 r10 = *(const f32x4*)(s1p + c0), r11 = *(const f32x4*)(s1p + c1);
            f32x4 r20 = *(const f32x4*)(s2p + c0), r21 = *(const f32x4*)(s2p + c1);
            f32x4 r30 = *(const f32x4*)(s3p + c0), r31 = *(const f32x4*)(s3p + c1);
            f32x4 a0, a1;
            #pragma unroll
            for (int i = 0; i < 4; ++i) {
                a0[i] = ((o0[g*4+i] * w0 + r10[i] * w1) + (r20[i] * w2 + r30[i] * w3)) * invl;
                a1[i] = ((o1[g*4+i] * w0 + r11[i] * w1) + (r21[i] * w2 + r31[i] * w3)) * invl;
            }
            *(f32x4*)(op + g * 8 + hi * 4)      = a0;
            *(f32x4*)(op + 32 + g * 8 + hi * 4) = a1;
        }
    }
}

// ---------------------------------------------------------------------------
// Rows q < fz[b]: reference softmax degenerates to uniform over ALL 2048 keys
// (scores all exactly -1e9 in fp32) -> out = mean(V). Overwrite them.
// ---------------------------------------------------------------------------
__global__ void fixup_kernel(const int* __restrict__ fz, const float* __restrict__ meanv,
                             float* __restrict__ out)
{
    const int bh = blockIdx.x;
    const int b  = bh >> 4;
    const int n  = fz[b];
    if (n <= 0) return;
    __shared__ float mv[DH];
    if (threadIdx.x < DH) mv[threadIdx.x] = meanv[bh * DH + threadIdx.x];
    __syncthreads();
    float* op = out + (long)bh * S_LEN * DH;
    for (int i = threadIdx.x; i < n * DH; i += 256) op[i] = mv[i & 63];
}

extern "C" void kernel_launch(void* const* d_in, const int* in_sizes, int n_in,
                              void* d_out, int out_size, void* d_ws, size_t ws_size,
                              hipStream_t stream)
{
    const float* Q   = (const float*)d_in[0];
    const float* K   = (const float*)d_in[1];
    const float* V   = (const float*)d_in[2];
    const int*   pad = (const int*)d_in[3];
    float* out = (float*)d_out;

    int*   fz    = (int*)d_ws;                          // 2 ints
    float* meanv = (float*)((char*)d_ws + 256);         // 32*64 f32
    float* bias  = (float*)((char*)d_ws + 8448);        // 2*2048 f32
    char*  Kimg  = (char*)d_ws + 32768;                 // 8 MB
    char*  Vimg  = Kimg + (size_t)NBH * NT * 4096;      // 8 MB

    fz_kernel<<<dim3(2), dim3(256), 0, stream>>>(pad, fz);
    bias_kernel<<<dim3(2), dim3(1024), 0, stream>>>(pad, bias);
    prep_kernel<<<dim3(NT, NBH), dim3(256), 0, stream>>>(K, V, Kimg, Vimg);
    attn_fwd8<<<dim3(2048), dim3(256), 0, stream>>>(Q, Kimg, Vimg, bias, out);
    meanv_kernel<<<dim3(NBH), dim3(1024), 0, stream>>>(V, fz, meanv);
    fixup_kernel<<<dim3(NBH), dim3(256), 0, stream>>>(fz, meanv, out);
}

// Round 12
// 123.549 us; speedup vs baseline: 2.7012x; 2.7012x over previous
//
#include <hip/hip_runtime.h>
#include <hip/hip_bf16.h>

#define S_LEN 2048
#define DH    64
#define NBH   32          // B*H
#define KVT   32          // keys per tile
#define NT    64          // tiles per bh (S/KVT)

typedef __attribute__((ext_vector_type(8)))  short short8;
typedef __attribute__((ext_vector_type(4)))  float f32x4;
typedef __attribute__((ext_vector_type(16))) float f32x16;

static __device__ __forceinline__ unsigned cvtpk_bf16(float a, float b) {
    unsigned r;
    asm("v_cvt_pk_bf16_f32 %0, %1, %2" : "=v"(r) : "v"(a), "v"(b));
    return r;
}
// cross-half (lane ^ 32) reductions — __shfl_xor is proven on this target.
// (permlane32_swap with two identical "+v" operands gets register-coalesced
//  into a self-swap, dropping each lane's own half. Do not reintroduce.)
static __device__ __forceinline__ float xor32_max(float x) {
    return fmaxf(x, __shfl_xor(x, 32));
}
static __device__ __forceinline__ float xor32_add(float x) {
    return x + __shfl_xor(x, 32);
}

// ---------------------------------------------------------------------------
// prep: K,V fp32 -> bf16 fragment images (4 KB per 32-key tile).
// Kimg tile: [key 0..31][128B = 64 d bf16]   (MFMA A-operand rows)
// Vimg tile: [d 0..63][64B = 32 keys bf16]   (V^T, PV A-operand rows)
// ---------------------------------------------------------------------------
__global__ __launch_bounds__(256)
void prep_kernel(const float* __restrict__ K, const float* __restrict__ V,
                 char* __restrict__ Kimg, char* __restrict__ Vimg)
{
    const int t = blockIdx.x, bh = blockIdx.y, tid = threadIdx.x;
    const long tileOff = ((long)bh * NT + t) * 4096;
    const float* kp = K + (long)bh * S_LEN * DH + t * KVT * DH;
    const float* vp = V + (long)bh * S_LEN * DH + t * KVT * DH;

    {   // K rows
        int key = tid >> 3, dc = tid & 7;
        f32x4 x = *(const f32x4*)(kp + key * 64 + dc * 8);
        f32x4 y = *(const f32x4*)(kp + key * 64 + dc * 8 + 4);
        uint4 w;
        w.x = cvtpk_bf16(x[0], x[1]);
        w.y = cvtpk_bf16(x[2], x[3]);
        w.z = cvtpk_bf16(y[0], y[1]);
        w.w = cvtpk_bf16(y[2], y[3]);
        *(uint4*)(Kimg + tileOff + key * 128 + dc * 16) = w;
    }
    {   // V^T rows (4x2 micro-transpose per thread)
        int vdg = tid & 15, vkq = tid >> 4;
        int d0 = vdg * 4, k0 = vkq * 2;
        f32x4 x0 = *(const f32x4*)(vp + k0 * 64 + d0);
        f32x4 x1 = *(const f32x4*)(vp + (k0 + 1) * 64 + d0);
        #pragma unroll
        for (int i = 0; i < 4; ++i)
            *(unsigned*)(Vimg + tileOff + (d0 + i) * 64 + k0 * 2) = cvtpk_bf16(x0[i], x1[i]);
    }
}

__global__ void fz_kernel(const int* __restrict__ pad, int* __restrict__ fz)
{
    int b = blockIdx.x;
    __shared__ int red[256];
    int local = S_LEN;
    for (int k = threadIdx.x; k < S_LEN; k += 256)
        if (pad[b * S_LEN + k] == 0 && k < local) local = k;
    red[threadIdx.x] = local;
    __syncthreads();
    for (int s = 128; s > 0; s >>= 1) {
        if (threadIdx.x < s) red[threadIdx.x] = min(red[threadIdx.x], red[threadIdx.x + s]);
        __syncthreads();
    }
    if (threadIdx.x == 0) fz[b] = red[0];
}

__global__ __launch_bounds__(1024)
void bias_kernel(const int* __restrict__ pad, float* __restrict__ bias)
{
    int b = blockIdx.x;
    #pragma unroll
    for (int i = 0; i < 2; ++i) {
        int k = threadIdx.x + i * 1024;
        bias[b * S_LEN + k] = pad[b * S_LEN + k] ? -1e30f : 0.f;
    }
}

__global__ __launch_bounds__(1024)
void meanv_kernel(const float* __restrict__ V, const int* __restrict__ fz,
                  float* __restrict__ meanv)
{
    const int bh = blockIdx.x;
    const int b  = bh >> 4;
    if (fz[b] <= 0) return;
    const int d4 = threadIdx.x & 15;
    const int kp = threadIdx.x >> 4;
    const float* vp = V + (long)bh * S_LEN * DH;
    f32x4 acc = (f32x4){0.f, 0.f, 0.f, 0.f};
    #pragma unroll 4
    for (int k = kp; k < S_LEN; k += 64)
        acc += *(const f32x4*)(vp + (long)k * DH + d4 * 4);
    __shared__ f32x4 red[64][16];
    red[kp][d4] = acc;
    __syncthreads();
    #pragma unroll
    for (int s = 32; s >= 1; s >>= 1) {
        if (kp < s) red[kp][d4] += red[kp + s][d4];
        __syncthreads();
    }
    if (kp == 0)
        *(f32x4*)(meanv + bh * DH + d4 * 4) = red[0][d4] * (1.0f / 2048.0f);
}

// ---------------------------------------------------------------------------
// attn v9: split-KV (r11 structure), register-budget fixed:
//   - __launch_bounds__(256) with NO min-waves clamp (r11's (256,3) forced
//     VGPR=84 -> 1.2 GB/launch of scratch spill traffic; WRITE_SIZE proved it)
//   - depth-1 prefetch, 2 banks (r6-proven loop shape): tiles are L2-resident
//     after the r10 mapping, so depth-1 covers the latency and saves 36 VGPRs.
// One block (4 waves) per (bh,bx); wave w owns tiles {w, w+4, ...} (longest
// chain 64 -> 16 tiles), then LDS merge with weights exp2(m_w - m*). Empty /
// all-masked waves get weight exactly 0 in fp32 -> junk wiped.
// ---------------------------------------------------------------------------
#define LOADK(dst, tt) do { const char* _p = KB + (long)(tt) * 4096 + lq * 128 + hi * 16; \
    dst[0] = *(const short8*)(_p);       dst[1] = *(const short8*)(_p + 32);  \
    dst[2] = *(const short8*)(_p + 64);  dst[3] = *(const short8*)(_p + 96); } while (0)
#define LOADV(dst, tt) do { const char* _p = VB + (long)(tt) * 4096 + lq * 64 + hi * 16; \
    dst[0] = *(const short8*)(_p);        dst[1] = *(const short8*)(_p + 32); \
    dst[2] = *(const short8*)(_p + 2048); dst[3] = *(const short8*)(_p + 2048 + 32); } while (0)
#define LOADB(dst, tt) do { const float* _p = biasB + (tt) * 32 + hi * 4; \
    dst[0] = *(const f32x4*)(_p);      dst[1] = *(const f32x4*)(_p + 8); \
    dst[2] = *(const f32x4*)(_p + 16); dst[3] = *(const f32x4*)(_p + 24); } while (0)

#define COMPUTE(TT, K_, V_, B_) do {                                          \
    f32x16 s0;                                                                \
    _Pragma("unroll")                                                         \
    for (int g = 0; g < 4; ++g) {                                             \
        f32x4 pb4 = B_[g];                                                    \
        _Pragma("unroll")                                                     \
        for (int i = 0; i < 4; ++i) s0[g * 4 + i] = pb4[i];                   \
    }                                                                         \
    __builtin_amdgcn_s_setprio(1);                                            \
    s0 = __builtin_amdgcn_mfma_f32_32x32x16_bf16(K_[0], bq[0], s0, 0, 0, 0);  \
    s0 = __builtin_amdgcn_mfma_f32_32x32x16_bf16(K_[1], bq[1], s0, 0, 0, 0);  \
    s0 = __builtin_amdgcn_mfma_f32_32x32x16_bf16(K_[2], bq[2], s0, 0, 0, 0);  \
    s0 = __builtin_amdgcn_mfma_f32_32x32x16_bf16(K_[3], bq[3], s0, 0, 0, 0);  \
    __builtin_amdgcn_s_setprio(0);                                            \
    if ((TT) == nkv - 1) {                                                    \
        _Pragma("unroll")                                                     \
        for (int rr = 0; rr < 16; ++rr) {                                     \
            int key_r = (rr & 3) + 8 * (rr >> 2) + 4 * hi;                    \
            if (key_r > lq) s0[rr] = -1e30f;                                  \
        }                                                                     \
    }                                                                         \
    float bmg[4];                                                             \
    _Pragma("unroll")                                                         \
    for (int g = 0; g < 4; ++g)                                               \
        bmg[g] = fmaxf(fmaxf(s0[g*4], s0[g*4+1]), fmaxf(s0[g*4+2], s0[g*4+3])); \
    float bm = fmaxf(fmaxf(bmg[0], bmg[1]), fmaxf(bmg[2], bmg[3]));           \
    bm = xor32_max(bm);                                                       \
    if (__any(bm > m_run + 8.0f)) {                                           \
        float mnew = fmaxf(m_run, bm);                                        \
        float c = exp2f(m_run - mnew);                                        \
        m_run = mnew; l_run *= c;                                             \
        _Pragma("unroll")                                                     \
        for (int rr = 0; rr < 16; ++rr) { o0[rr] *= c; o1[rr] *= c; }         \
    }                                                                         \
    _Pragma("unroll")                                                         \
    for (int rr = 0; rr < 16; ++rr) s0[rr] = exp2f(s0[rr] - m_run);           \
    float rsg[4];                                                             \
    _Pragma("unroll")                                                         \
    for (int g = 0; g < 4; ++g)                                               \
        rsg[g] = (s0[g*4] + s0[g*4+1]) + (s0[g*4+2] + s0[g*4+3]);             \
    float rs = (rsg[0] + rsg[1]) + (rsg[2] + rsg[3]);                         \
    l_run += xor32_add(rs);                                                   \
    short8 pfr0, pfr1;                                                        \
    {                                                                         \
        unsigned a0 = cvtpk_bf16(s0[0], s0[1]), b0 = cvtpk_bf16(s0[4], s0[5]);\
        asm("v_permlane32_swap_b32 %0, %1" : "+v"(a0), "+v"(b0));             \
        unsigned a1 = cvtpk_bf16(s0[2], s0[3]), b1 = cvtpk_bf16(s0[6], s0[7]);\
        asm("v_permlane32_swap_b32 %0, %1" : "+v"(a1), "+v"(b1));             \
        union { short8 s8; unsigned u[4]; } u;                                \
        u.u[0] = a0; u.u[1] = a1; u.u[2] = b0; u.u[3] = b1;                   \
        pfr0 = u.s8;                                                          \
    }                                                                         \
    {                                                                         \
        unsigned a0 = cvtpk_bf16(s0[8], s0[9]),  b0 = cvtpk_bf16(s0[12], s0[13]); \
        asm("v_permlane32_swap_b32 %0, %1" : "+v"(a0), "+v"(b0));             \
        unsigned a1 = cvtpk_bf16(s0[10], s0[11]), b1 = cvtpk_bf16(s0[14], s0[15]); \
        asm("v_permlane32_swap_b32 %0, %1" : "+v"(a1), "+v"(b1));             \
        union { short8 s8; unsigned u[4]; } u;                                \
        u.u[0] = a0; u.u[1] = a1; u.u[2] = b0; u.u[3] = b1;                   \
        pfr1 = u.s8;                                                          \
    }                                                                         \
    __builtin_amdgcn_s_setprio(1);                                            \
    o0 = __builtin_amdgcn_mfma_f32_32x32x16_bf16(V_[0], pfr0, o0, 0, 0, 0);   \
    o0 = __builtin_amdgcn_mfma_f32_32x32x16_bf16(V_[1], pfr1, o0, 0, 0, 0);   \
    o1 = __builtin_amdgcn_mfma_f32_32x32x16_bf16(V_[2], pfr0, o1, 0, 0, 0);   \
    o1 = __builtin_amdgcn_mfma_f32_32x32x16_bf16(V_[3], pfr1, o1, 0, 0, 0);   \
    __builtin_amdgcn_s_setprio(0);                                            \
} while (0)

__global__ __launch_bounds__(256)
void attn_fwd9(const float* __restrict__ Q, const char* __restrict__ Kimg,
               const char* __restrict__ Vimg, const float* __restrict__ bias,
               float* __restrict__ out)
{
    __shared__ float mW[4][32];
    __shared__ float lW[4][32];
    __shared__ __align__(16) char ldsO[3][8192];   // waves 1..3: O (8KB each)

    const int tid  = threadIdx.x;
    const int lane = tid & 63;
    const int w    = tid >> 6;
    const int lq   = lane & 31, hi = lane >> 5;

    // r10 mapping (verbatim): XCD locality + balance, bijection over 2048
    const int gid = blockIdx.x;
    const int x   = gid & 7;
    const int c   = (gid >> 3) & 31;
    const int m   = (gid >> 8) & 3;
    const int s   = gid >> 10;
    const int bh  = x + 8 * (c & 3);
    const int e   = ((c >> 2) << 2) | m;     // 0..31
    const int bx  = s ? 63 - e : e;
    const int q0  = bx * 32;
    const int nkv = bx + 1;
    const long base = (long)bh * S_LEN * DH;

    const char*  KB    = Kimg + (long)bh * NT * 4096;
    const char*  VB    = Vimg + (long)bh * NT * 4096;
    const float* biasB = bias + (bh >> 4) * S_LEN;

    // Q fragments (B operand), scale = (1/8)*log2(e) folded
    const float QS = 0.18033688011112042f;
    short8 bq[4];
    {
        const float* qp = Q + base + (long)(q0 + lq) * DH;
        #pragma unroll
        for (int ss = 0; ss < 4; ++ss) {
            int d0 = ss * 16 + hi * 8;
            f32x4 xx = *(const f32x4*)(qp + d0);
            f32x4 yy = *(const f32x4*)(qp + d0 + 4);
            union { short8 s8; unsigned u4[4]; } uu;
            uu.u4[0] = cvtpk_bf16(xx[0] * QS, xx[1] * QS);
            uu.u4[1] = cvtpk_bf16(xx[2] * QS, xx[3] * QS);
            uu.u4[2] = cvtpk_bf16(yy[0] * QS, yy[1] * QS);
            uu.u4[3] = cvtpk_bf16(yy[2] * QS, yy[3] * QS);
            bq[ss] = uu.s8;
        }
    }

    f32x16 o0, o1;
    #pragma unroll
    for (int rr = 0; rr < 16; ++rr) { o0[rr] = 0.f; o1[rr] = 0.f; }
    float m_run = -1e30f, l_run = 0.f;

    // this wave's tiles: w, w+4, w+8, ...  (longest chain = 16)
    const int nw = (w < nkv) ? ((nkv - w + 3) >> 2) : 0;
#define TIDX(i) (w + 4 * (i))

    if (nw > 0) {
        // two prefetch banks (static indices only — rule #20)
        short8 kA[4], kB_[4], vA[4], vB_[4];
        f32x4  bA[4], bB_[4];

        LOADB(bA, TIDX(0)); LOADK(kA, TIDX(0)); LOADV(vA, TIDX(0));
        int i = 0;
        for (;;) {
            if (i + 1 < nw) { LOADB(bB_, TIDX(i+1)); LOADK(kB_, TIDX(i+1)); LOADV(vB_, TIDX(i+1)); }
            COMPUTE(TIDX(i), kA, vA, bA);
            ++i; if (i >= nw) break;
            if (i + 1 < nw) { LOADB(bA, TIDX(i+1)); LOADK(kA, TIDX(i+1)); LOADV(vA, TIDX(i+1)); }
            COMPUTE(TIDX(i), kB_, vB_, bB_);
            ++i; if (i >= nw) break;
        }
    }

    // ---- merge ----
    mW[w][lq] = m_run;
    lW[w][lq] = l_run;
    if (w > 0) {
        char* dst = ldsO[w - 1] + lane * 128;
        #pragma unroll
        for (int g = 0; g < 4; ++g) {
            f32x4 a0, a1;
            #pragma unroll
            for (int i = 0; i < 4; ++i) { a0[i] = o0[g * 4 + i]; a1[i] = o1[g * 4 + i]; }
            *(f32x4*)(dst + ((g       ^ (lane & 7)) * 16)) = a0;
            *(f32x4*)(dst + (((4 + g) ^ (lane & 7)) * 16)) = a1;
        }
    }
    __syncthreads();
    if (w == 0) {
        float m0 = mW[0][lq], m1 = mW[1][lq], m2 = mW[2][lq], m3 = mW[3][lq];
        float ms = fmaxf(fmaxf(m0, m1), fmaxf(m2, m3));
        float w0 = exp2f(m0 - ms), w1 = exp2f(m1 - ms);
        float w2 = exp2f(m2 - ms), w3 = exp2f(m3 - ms);
        float ls = ((w0 * lW[0][lq] + w1 * lW[1][lq]) + (w2 * lW[2][lq] + w3 * lW[3][lq]));
        float invl = 1.0f / ls;

        const char* s1p = ldsO[0] + lane * 128;
        const char* s2p = ldsO[1] + lane * 128;
        const char* s3p = ldsO[2] + lane * 128;
        float* op = out + base + (long)(q0 + lq) * DH;
        #pragma unroll
        for (int g = 0; g < 4; ++g) {
            int c0 = (g       ^ (lane & 7)) * 16;
            int c1 = ((4 + g) ^ (lane & 7)) * 16;
            f32x4 r10 = *(const f32x4*)(s1p + c0), r11 = *(const f32x4*)(s1p + c1);
            f32x4 r20 = *(const f32x4*)(s2p + c0), r21 = *(const f32x4*)(s2p + c1);
            f32x4 r30 = *(const f32x4*)(s3p + c0), r31 = *(const f32x4*)(s3p + c1);
            f32x4 a0, a1;
            #pragma unroll
            for (int i = 0; i < 4; ++i) {
                a0[i] = ((o0[g*4+i] * w0 + r10[i] * w1) + (r20[i] * w2 + r30[i] * w3)) * invl;
                a1[i] = ((o1[g*4+i] * w0 + r11[i] * w1) + (r21[i] * w2 + r31[i] * w3)) * invl;
            }
            *(f32x4*)(op + g * 8 + hi * 4)      = a0;
            *(f32x4*)(op + 32 + g * 8 + hi * 4) = a1;
        }
    }
}

// ---------------------------------------------------------------------------
// Rows q < fz[b]: reference softmax degenerates to uniform over ALL 2048 keys
// (scores all exactly -1e9 in fp32) -> out = mean(V). Overwrite them.
// ---------------------------------------------------------------------------
__global__ void fixup_kernel(const int* __restrict__ fz, const float* __restrict__ meanv,
                             float* __restrict__ out)
{
    const int bh = blockIdx.x;
    const int b  = bh >> 4;
    const int n  = fz[b];
    if (n <= 0) return;
    __shared__ float mv[DH];
    if (threadIdx.x < DH) mv[threadIdx.x] = meanv[bh * DH + threadIdx.x];
    __syncthreads();
    float* op = out + (long)bh * S_LEN * DH;
    for (int i = threadIdx.x; i < n * DH; i += 256) op[i] = mv[i & 63];
}

extern "C" void kernel_launch(void* const* d_in, const int* in_sizes, int n_in,
                              void* d_out, int out_size, void* d_ws, size_t ws_size,
                              hipStream_t stream)
{
    const float* Q   = (const float*)d_in[0];
    const float* K   = (const float*)d_in[1];
    const float* V   = (const float*)d_in[2];
    const int*   pad = (const int*)d_in[3];
    float* out = (float*)d_out;

    int*   fz    = (int*)d_ws;                          // 2 ints
    float* meanv = (float*)((char*)d_ws + 256);         // 32*64 f32
    float* bias  = (float*)((char*)d_ws + 8448);        // 2*2048 f32
    char*  Kimg  = (char*)d_ws + 32768;                 // 8 MB
    char*  Vimg  = Kimg + (size_t)NBH * NT * 4096;      // 8 MB

    fz_kernel<<<dim3(2), dim3(256), 0, stream>>>(pad, fz);
    bias_kernel<<<dim3(2), dim3(1024), 0, stream>>>(pad, bias);
    prep_kernel<<<dim3(NT, NBH), dim3(256), 0, stream>>>(K, V, Kimg, Vimg);
    attn_fwd9<<<dim3(2048), dim3(256), 0, stream>>>(Q, Kimg, Vimg, bias, out);
    meanv_kernel<<<dim3(NBH), dim3(1024), 0, stream>>>(V, fz, meanv);
    fixup_kernel<<<dim3(NBH), dim3(256), 0, stream>>>(fz, meanv, out);
}